// Round 12
// baseline (478.876 us; speedup 1.0000x reference)
//
#include <hip/hip_runtime.h>
#include <hip/hip_bf16.h>
#include <math.h>

typedef unsigned short u16;
using short8  = __attribute__((ext_vector_type(8))) short;
using ushort8 = __attribute__((ext_vector_type(8))) unsigned short;
using f32x4   = __attribute__((ext_vector_type(4))) float;

static constexpr int NNODE = 50000;
static constexpr int NEDGE = 600000;
static constexpr float EPSC   = 0.1f;
static constexpr float GAMMAC = 0.1f;

// ---- workspace layout (float-index offsets) ----
static constexpr long long O_DINV   = 0;                         // float 50000
static constexpr long long O_DEGI   = 50000;                     // int 50000
static constexpr long long O_ROWPTR = 100000;                    // int 50001
static constexpr long long O_CURSOR = 150004;                    // int 50000
static constexpr long long O_PSUM   = 200004;                    // int 256
static constexpr long long O_ECSR   = 200260;                    // int2 600000 (1.2M fl)
// bf16 weights
static constexpr long long O_WHB    = 1400260;                   // 32768 bf16
static constexpr long long O_G1TB   = O_WHB  + 16384;            // 16384 bf16
static constexpr long long O_AW1B   = O_G1TB + 8192;             // 16384 bf16
static constexpr long long O_W2B    = O_AW1B + 8192;             // 8192 bf16
static constexpr long long O_AW2B   = O_W2B  + 4096;             // 4096 bf16
static constexpr long long O_G2TB   = O_AW2B + 2048;             // 4096 bf16
static constexpr long long O_WFCB   = O_G2TB + 2048;             // 2560 bf16
// big buffers (bf16 activations)
static constexpr long long O_GB     = 3450004;                   // bf16 6.4M (g)
static constexpr long long O_UB     = O_GB   + 3200000;          // bf16 6.4M (u)
static constexpr long long O_HB0    = O_UB   + 3200000;          // bf16 6.4M
static constexpr long long O_HB1    = O_HB0  + 3200000;          // bf16 6.4M

__device__ __forceinline__ float bf2f(u16 u) {
    return __uint_as_float(((unsigned)u) << 16);
}
__device__ __forceinline__ u16 f2bf(float f) {
    unsigned u = __float_as_uint(f);
    return (u16)((u + 0x7FFFu + ((u >> 16) & 1u)) >> 16);
}

// ---- weight prep (bf16 convert/antisym/transpose) + degi zero (fused) ----
__global__ __launch_bounds__(256) void prep_kernel(
    const float* __restrict__ w_hid, const float* __restrict__ W_a1,
    const float* __restrict__ gcn1,  const float* __restrict__ w2,
    const float* __restrict__ W_a2,  const float* __restrict__ gcn2,
    const float* __restrict__ wfc,   float* __restrict__ ws)
{
    int j = blockIdx.x * 256 + threadIdx.x;
    if (j < 32768) { ((u16*)(ws+O_WHB))[j] = f2bf(w_hid[j]); return; } j -= 32768;
    if (j < 16384) { int r=j>>7, c=j&127; ((u16*)(ws+O_G1TB))[j] = f2bf(gcn1[c*128+r]); return; } j -= 16384;
    if (j < 16384) { int r=j>>7, c=j&127;
                     ((u16*)(ws+O_AW1B))[j] = f2bf(W_a1[r*128+c] - W_a1[c*128+r] - (r==c?GAMMAC:0.f));
                     return; } j -= 16384;
    if (j < 8192)  { ((u16*)(ws+O_W2B))[j] = f2bf(w2[j]); return; } j -= 8192;
    if (j < 4096)  { int r=j>>6, c=j&63;
                     ((u16*)(ws+O_AW2B))[j] = f2bf(W_a2[r*64+c] - W_a2[c*64+r] - (r==c?GAMMAC:0.f));
                     return; } j -= 4096;
    if (j < 4096)  { int r=j>>6, c=j&63; ((u16*)(ws+O_G2TB))[j] = f2bf(gcn2[c*64+r]); return; } j -= 4096;
    if (j < 2560)  { ((u16*)(ws+O_WFCB))[j] = f2bf(wfc[j]); return; } j -= 2560;
    if (j < NNODE) { ((int*)(ws+O_DEGI))[j] = 0; return; }   // fused degi zero
}

// ---- CSR build ----
__global__ __launch_bounds__(256) void deg_count_kernel(const int* __restrict__ ei,
                                                        int* __restrict__ degi) {
    int e = blockIdx.x * 256 + threadIdx.x;
    if (e < NEDGE) atomicAdd(&degi[ei[NEDGE + e]], 1);
}
__global__ __launch_bounds__(256) void psum_kernel(const int* __restrict__ degi,
                                                   float* __restrict__ dinv,
                                                   int* __restrict__ psum) {
    int i = blockIdx.x * 256 + threadIdx.x;
    int v = (i < NNODE) ? degi[i] : 0;
    if (i < NNODE) dinv[i] = rsqrtf(1.0f + (float)v);  // +1 self loop
    int t = v;
    #pragma unroll
    for (int o = 32; o > 0; o >>= 1) t += __shfl_xor(t, o);
    __shared__ int s[4];
    int lane = threadIdx.x & 63, w = threadIdx.x >> 6;
    if (lane == 0) s[w] = t;
    __syncthreads();
    if (threadIdx.x == 0) psum[blockIdx.x] = s[0] + s[1] + s[2] + s[3];
}
__global__ __launch_bounds__(256) void scan_psum_kernel(int* __restrict__ psum, int nb) {
    int t = threadIdx.x;
    int v = (t < nb) ? psum[t] : 0;
    int lane = t & 63, w = t >> 6;
    int x = v;
    #pragma unroll
    for (int o = 1; o < 64; o <<= 1) { int u = __shfl_up(x, o); if (lane >= o) x += u; }
    __shared__ int ws4[4];
    if (lane == 63) ws4[w] = x;
    __syncthreads();
    int woff = 0;
    for (int i = 0; i < w; ++i) woff += ws4[i];
    psum[t] = woff + x - v;   // exclusive
}
__global__ __launch_bounds__(256) void scan_apply_kernel(const int* __restrict__ degi,
                                                         const int* __restrict__ psum,
                                                         int* __restrict__ rowptr,
                                                         int* __restrict__ cursor) {
    int i = blockIdx.x * 256 + threadIdx.x;
    int v = (i < NNODE) ? degi[i] : 0;
    int lane = threadIdx.x & 63, w = threadIdx.x >> 6;
    int x = v;
    #pragma unroll
    for (int o = 1; o < 64; o <<= 1) { int u = __shfl_up(x, o); if (lane >= o) x += u; }
    __shared__ int ws4[4];
    if (lane == 63) ws4[w] = x;
    __syncthreads();
    int woff = 0;
    for (int k = 0; k < w; ++k) woff += ws4[k];
    int run = psum[blockIdx.x] + woff + x - v;
    if (i < NNODE) { rowptr[i] = run; cursor[i] = run; }
    if (i == NNODE - 1) rowptr[NNODE] = run + v;
}
__global__ __launch_bounds__(256) void fill_kernel(const int* __restrict__ ei,
                                                   const float* __restrict__ dinv,
                                                   int* __restrict__ cursor,
                                                   int2* __restrict__ ecsr) {
    int e = blockIdx.x * 256 + threadIdx.x;
    if (e >= NEDGE) return;
    int s = ei[e], d = ei[NEDGE + e];
    int pos = atomicAdd(&cursor[d], 1);
    int2 v;
    v.x = s;
    v.y = __float_as_int(dinv[s] * dinv[d]);
    ecsr[pos] = v;
}

// ---- MFMA GEMM: LDS-staged B, LDS-transposed epilogue ----
// DUAL=1: two passes (Bt->outB, Bt2->outB2), raw bf16 writes, A loaded once.
// EPI: 0 none(+bias), 1 leaky(+bias), 3: fused log_softmax -> outF.
template<int KS, int NT, int AF32, int LOADACT, int EPI, int DUAL>
__global__ __launch_bounds__(256, 4) void mgemm(
    const void* __restrict__ Araw,
    const u16* __restrict__ Bt,
    const u16* __restrict__ Bt2,
    const float* __restrict__ bias,
    float* __restrict__ outF,
    u16* __restrict__ outB,
    u16* __restrict__ outB2,
    int M, int Nn, int ldc)
{
    constexpr int K    = KS * 32;
    constexpr int KCHU = (K > 128) ? 128 : K;
    constexpr int KC   = KCHU / 32;
    constexpr int NCH  = K / KCHU;
    constexpr int P    = KCHU + 8;
    constexpr int ROWS = NT * 16;
    constexpr int CW   = NT * 16 + 1;
    constexpr int BSZ  = ROWS * P * 2;
    constexpr int ASZ  = 64 * CW * 4;
    constexpr int SMEM = BSZ > ASZ ? BSZ : ASZ;
    __shared__ __align__(16) char smem[SMEM];
    u16*   bl   = (u16*)smem;
    float* accL = (float*)smem;

    const int wave = threadIdx.x >> 6;
    const int lane = threadIdx.x & 63;
    const int m = lane & 15, q = lane >> 4;
    const int rowbase = blockIdx.x * 64 + wave * 16;
    const int row = rowbase + m;
    const bool rok = row < M;
    const short8 z8 = {0,0,0,0,0,0,0,0};

    short8 af[KS];
    if (AF32) {
        const float* apf = (const float*)Araw + (long long)row * K;
        #pragma unroll
        for (int k = 0; k < KS; ++k) {
            short8 t = z8;
            if (rok) {
                const float4* p = (const float4*)(apf + (k * 4 + q) * 8);
                float4 a = p[0], b = p[1];
                t[0]=(short)f2bf(a.x); t[1]=(short)f2bf(a.y); t[2]=(short)f2bf(a.z); t[3]=(short)f2bf(a.w);
                t[4]=(short)f2bf(b.x); t[5]=(short)f2bf(b.y); t[6]=(short)f2bf(b.z); t[7]=(short)f2bf(b.w);
            }
            af[k] = t;
        }
    } else {
        const short8* ap = (const short8*)((const u16*)Araw + (long long)row * K);
        #pragma unroll
        for (int k = 0; k < KS; ++k) af[k] = rok ? ap[k * 4 + q] : z8;
    }
    if (LOADACT) {
        #pragma unroll
        for (int k = 0; k < KS; ++k)
            #pragma unroll
            for (int e = 0; e < 8; ++e) {
                float f = bf2f((u16)af[k][e]);
                f = f > 0.f ? f : 0.01f * f;
                af[k][e] = (short)f2bf(f);
            }
    }

    #pragma unroll
    for (int pass = 0; pass <= DUAL; ++pass) {
        const u16* Bcur = pass ? Bt2 : Bt;
        u16* outCur = pass ? outB2 : outB;
        if (pass) __syncthreads();     // LDS reuse across passes

        f32x4 acc[NT];
        #pragma unroll
        for (int j = 0; j < NT; ++j) acc[j] = (f32x4){0.f,0.f,0.f,0.f};

        for (int ch = 0; ch < NCH; ++ch) {
            if (ch) __syncthreads();
            constexpr int CHUNKS = ROWS * (KCHU / 8);
            for (int t = threadIdx.x; t < CHUNKS; t += 256) {
                int r = t / (KCHU / 8), c = t - r * (KCHU / 8);
                short8 v = z8;
                if (r < Nn) v = *(const short8*)&Bcur[(long long)r * K + ch * KCHU + c * 8];
                *(short8*)&bl[r * P + c * 8] = v;
            }
            __syncthreads();
            #pragma unroll
            for (int j = 0; j < NT; ++j) {
                #pragma unroll
                for (int k = 0; k < KC; ++k) {
                    short8 bf_ = *(const short8*)&bl[(j * 16 + m) * P + k * 32 + q * 8];
                    acc[j] = __builtin_amdgcn_mfma_f32_16x16x32_bf16(af[ch * KC + k], bf_, acc[j], 0, 0, 0);
                }
            }
        }

        __syncthreads();            // reuse LDS for acc transpose
        #pragma unroll
        for (int j = 0; j < NT; ++j)
            #pragma unroll
            for (int r = 0; r < 4; ++r)
                accL[(wave * 16 + q * 4 + r) * CW + j * 16 + m] = acc[j][r];
        __syncthreads();

        if (EPI == 3) {
            // fused log-softmax over Nn cols per row (all in LDS)
            float mrow = 0.f, lrow = 0.f;
            if (lane < 16) {
                const float* rp = &accL[(wave * 16 + lane) * CW];
                float mx = -1e30f;
                for (int c = 0; c < Nn; ++c) mx = fmaxf(mx, rp[c] + bias[c]);
                float s = 0.f;
                for (int c = 0; c < Nn; ++c) s += expf(rp[c] + bias[c] - mx);
                mrow = mx; lrow = logf(s);
            }
            for (int rl = 0; rl < 16; ++rl) {
                float mm = __shfl(mrow, rl);
                float ll = __shfl(lrow, rl);
                int rowD = rowbase + rl;
                if (rowD < M && lane < Nn) {
                    float v = accL[(wave * 16 + rl) * CW + lane] + bias[lane];
                    outF[(long long)rowD * ldc + lane] = v - mm - ll;
                }
            }
            return;
        }

        const int c0 = lane * 2;
        if (c0 < NT * 16) {
            float2 bv = {0.f, 0.f};
            if (EPI != 0 || !DUAL) {
                if (bias) {
                    if (c0 < Nn)     bv.x = bias[c0];
                    if (c0 + 1 < Nn) bv.y = bias[c0 + 1];
                }
            }
            #pragma unroll
            for (int rl = 0; rl < 16; ++rl) {
                int rowD = rowbase + rl;
                if (rowD >= M) continue;
                float2 v = *(const float2*)&accL[(wave * 16 + rl) * CW + c0];
                long long o = (long long)rowD * ldc + c0;
                v.x += bv.x; v.y += bv.y;
                if (EPI == 1) {
                    v.x = v.x > 0.f ? v.x : 0.01f * v.x;
                    v.y = v.y > 0.f ? v.y : 0.01f * v.y;
                }
                if (c0 + 1 < Nn) {
                    if (outCur) { ushort2 ob; ob.x = f2bf(v.x); ob.y = f2bf(v.y);
                                  *(ushort2*)&outCur[o] = ob; }
                    if (!pass && outF) { *(float2*)&outF[o] = v; }
                } else if (c0 < Nn) {
                    if (outCur) outCur[o] = f2bf(v.x);
                    if (!pass && outF) outF[o] = v.x;
                }
            }
        }
    }
}

// ---- CSR gather + fused antisym update ----
// agg (fp32 regs) = sum_nbr w*g[nbr] + wself*g[node];
// h_new = h + EPS*tanh(u + agg + bias)  -> hnB (bf16)
template<int HD>
__global__ __launch_bounds__(256) void gather_upd_kernel(
    const int* __restrict__ rowptr, const int2* __restrict__ ecsr,
    const float* __restrict__ dinv,
    const u16* __restrict__ gB, const u16* __restrict__ uB,
    const u16* __restrict__ hB, const float* __restrict__ bias,
    u16* __restrict__ hnB)
{
    int node = (blockIdx.x * 256 + threadIdx.x) >> 6;
    int lane = threadIdx.x & 63;
    if (node >= NNODE) return;
    const int qr = lane >> 4, l4 = lane & 15;
    const int r0 = rowptr[node], r1 = rowptr[node + 1];
    const float wself = dinv[node] * dinv[node];
    constexpr int EL = (HD == 128) ? 8 : 4;

    float a[EL];
    #pragma unroll
    for (int i = 0; i < EL; ++i) a[i] = 0.f;
    if (qr == 0) {
        if (HD == 128) {
            ushort8 gs = *(const ushort8*)&gB[(long long)node * 128 + l4 * 8];
            #pragma unroll
            for (int i = 0; i < 8; ++i) a[i] = bf2f(gs[i]) * wself;
        } else {
            ushort4 gs = *(const ushort4*)&gB[(long long)node * 64 + l4 * 4];
            a[0] = bf2f(gs.x) * wself; a[1] = bf2f(gs.y) * wself;
            a[2] = bf2f(gs.z) * wself; a[3] = bf2f(gs.w) * wself;
        }
    }

    for (int base = r0; base < r1; base += 64) {
        int idx = base + lane;
        int cs = 0; float cw = 0.f;
        if (idx < r1) { int2 ev = ecsr[idx]; cs = ev.x; cw = __int_as_float(ev.y); }
        int cnt = min(64, r1 - base);
        for (int j = 0; j < cnt; j += 4) {
            int jj = j + qr;
            int   s = __shfl(cs, jj);
            float w = __shfl(cw, jj);
            if (HD == 128) {
                ushort8 gv = *(const ushort8*)&gB[(long long)s * 128 + l4 * 8];
                #pragma unroll
                for (int i = 0; i < 8; ++i) a[i] += bf2f(gv[i]) * w;
            } else {
                ushort4 gv = *(const ushort4*)&gB[(long long)s * 64 + l4 * 4];
                a[0] += bf2f(gv.x) * w; a[1] += bf2f(gv.y) * w;
                a[2] += bf2f(gv.z) * w; a[3] += bf2f(gv.w) * w;
            }
        }
    }

    #pragma unroll
    for (int i = 0; i < EL; ++i) {
        a[i] += __shfl_xor(a[i], 16);
        a[i] += __shfl_xor(a[i], 32);
    }

    if (qr == 0) {
        long long o = (long long)node * HD + l4 * EL;
        if (HD == 128) {
            ushort8 uu = *(const ushort8*)&uB[o];
            ushort8 hh = *(const ushort8*)&hB[o];
            ushort8 on;
            #pragma unroll
            for (int i = 0; i < 8; ++i) {
                float hn = bf2f(hh[i]) + EPSC * tanhf(a[i] + bf2f(uu[i]) + bias[l4 * 8 + i]);
                on[i] = f2bf(hn);
            }
            *(ushort8*)&hnB[o] = on;
        } else {
            ushort4 uu = *(const ushort4*)&uB[o];
            ushort4 hh = *(const ushort4*)&hB[o];
            ushort4 on;
            on.x = f2bf(bf2f(hh.x) + EPSC * tanhf(a[0] + bf2f(uu.x) + bias[l4 * 4 + 0]));
            on.y = f2bf(bf2f(hh.y) + EPSC * tanhf(a[1] + bf2f(uu.y) + bias[l4 * 4 + 1]));
            on.z = f2bf(bf2f(hh.z) + EPSC * tanhf(a[2] + bf2f(uu.z) + bias[l4 * 4 + 2]));
            on.w = f2bf(bf2f(hh.w) + EPSC * tanhf(a[3] + bf2f(uu.w) + bias[l4 * 4 + 3]));
            *(ushort4*)&hnB[o] = on;
        }
    }
}

extern "C" void kernel_launch(void* const* d_in, const int* in_sizes, int n_in,
                              void* d_out, int out_size, void* d_ws, size_t ws_size,
                              hipStream_t stream) {
    const float* x     = (const float*)d_in[0];
    const int*   ei    = (const int*)d_in[1];
    const float* w_hid = (const float*)d_in[2];
    const float* b_hid = (const float*)d_in[3];
    const float* W_a1  = (const float*)d_in[4];
    const float* gcn1  = (const float*)d_in[5];
    const float* b_a1  = (const float*)d_in[6];
    const float* w2    = (const float*)d_in[7];
    const float* b2    = (const float*)d_in[8];
    const float* W_a2  = (const float*)d_in[9];
    const float* gcn2  = (const float*)d_in[10];
    const float* b_a2  = (const float*)d_in[11];
    const float* wfc   = (const float*)d_in[12];
    const float* bfc   = (const float*)d_in[13];
    float* ws = (float*)d_ws;
    float* out = (float*)d_out;

    float* dinv   = ws + O_DINV;
    int*   degi   = (int*)(ws + O_DEGI);
    int*   rowptr = (int*)(ws + O_ROWPTR);
    int*   cursor = (int*)(ws + O_CURSOR);
    int*   psum   = (int*)(ws + O_PSUM);
    int2*  ecsr   = (int2*)(ws + O_ECSR);
    u16* whB  = (u16*)(ws + O_WHB);
    u16* g1tB = (u16*)(ws + O_G1TB);
    u16* aw1B = (u16*)(ws + O_AW1B);
    u16* w2B  = (u16*)(ws + O_W2B);
    u16* aw2B = (u16*)(ws + O_AW2B);
    u16* g2tB = (u16*)(ws + O_G2TB);
    u16* wfcB = (u16*)(ws + O_WFCB);
    u16* gBuf = (u16*)(ws + O_GB);
    u16* uBuf = (u16*)(ws + O_UB);
    u16* hB0  = (u16*)(ws + O_HB0);
    u16* hB1  = (u16*)(ws + O_HB1);

    const int nScanB = (NNODE + 255) / 256;  // 196

    prep_kernel<<<(84480 + NNODE + 255) / 256, 256, 0, stream>>>(
        w_hid, W_a1, gcn1, w2, W_a2, gcn2, wfc, ws);
    deg_count_kernel<<<(NEDGE + 255) / 256, 256, 0, stream>>>(ei, degi);
    psum_kernel<<<nScanB, 256, 0, stream>>>(degi, dinv, psum);
    scan_psum_kernel<<<1, 256, 0, stream>>>(psum, nScanB);
    scan_apply_kernel<<<nScanB, 256, 0, stream>>>(degi, psum, rowptr, cursor);
    fill_kernel<<<(NEDGE + 255) / 256, 256, 0, stream>>>(ei, dinv, cursor, ecsr);

    const int gB = (NNODE + 63) / 64;       // 782 row-blocks
    const int gatherBlocks = (NNODE * 64 + 255) / 256;

    // h = leaky_relu(x @ w_hid^T + b_hid) -> hB0
    mgemm<8, 8, 1, 0, 1, 0><<<gB, 256, 0, stream>>>(
        x, whB, nullptr, b_hid, nullptr, hB0, nullptr, NNODE, 128, 128);

    // conv1: 3 iterations — dual GEMM (g,u) + gather-with-update
    u16* hBc = hB0; u16* hBo = hB1;
    for (int it = 0; it < 3; ++it) {
        mgemm<4, 8, 0, 0, 0, 1><<<gB, 256, 0, stream>>>(
            hBc, g1tB, aw1B, nullptr, nullptr, gBuf, uBuf, NNODE, 128, 128);
        gather_upd_kernel<128><<<gatherBlocks, 256, 0, stream>>>(
            rowptr, ecsr, dinv, gBuf, uBuf, hBc, b_a1, hBo);
        u16* tb = hBc; hBc = hBo; hBo = tb;
    }

    // h2 = leaky_relu(leaky_relu(h) @ w2^T + b2) -> hBo
    mgemm<4, 4, 0, 1, 1, 0><<<gB, 256, 0, stream>>>(
        hBc, w2B, nullptr, b2, nullptr, hBo, nullptr, NNODE, 64, 64);
    u16* h2B = hBo;
    u16* spB = hBc;   // dead, reusable

    // conv2: 1 iteration — dual GEMM + gather-update
    mgemm<2, 4, 0, 0, 0, 1><<<gB, 256, 0, stream>>>(
        h2B, g2tB, aw2B, nullptr, nullptr, gBuf, uBuf, NNODE, 64, 64);
    gather_upd_kernel<64><<<gatherBlocks, 256, 0, stream>>>(
        rowptr, ecsr, dinv, gBuf, uBuf, h2B, b_a2, spB);

    // z = h2n @ w_fc^T + b_fc, fused log-softmax -> out (fp32)
    mgemm<2, 3, 0, 0, 3, 0><<<gB, 256, 0, stream>>>(
        spB, wfcB, nullptr, bfc, out, nullptr, nullptr, NNODE, 40, 40);
}

// Round 13
// 432.726 us; speedup vs baseline: 1.1066x; 1.1066x over previous
//
#include <hip/hip_runtime.h>
#include <hip/hip_bf16.h>
#include <math.h>

typedef unsigned short u16;
using short8  = __attribute__((ext_vector_type(8))) short;
using ushort8 = __attribute__((ext_vector_type(8))) unsigned short;
using f32x4   = __attribute__((ext_vector_type(4))) float;

static constexpr int NNODE = 50000;
static constexpr int NEDGE = 600000;
static constexpr float EPSC   = 0.1f;
static constexpr float GAMMAC = 0.1f;

// ---- workspace layout (float-index offsets) ----
static constexpr long long O_DINV   = 0;                         // float 50000
static constexpr long long O_DEGI   = 50000;                     // int 50000
static constexpr long long O_ROWPTR = 100000;                    // int 50001
static constexpr long long O_CURSOR = 150004;                    // int 50000
static constexpr long long O_PSUM   = 200004;                    // int 256
static constexpr long long O_ECSR   = 200260;                    // int2 600000 (1.2M fl)
// bf16 weights
static constexpr long long O_WHB    = 1400260;                   // 32768 bf16
static constexpr long long O_G1TB   = O_WHB  + 16384;            // 16384 bf16
static constexpr long long O_AW1B   = O_G1TB + 8192;             // 16384 bf16
static constexpr long long O_W2B    = O_AW1B + 8192;             // 8192 bf16
static constexpr long long O_AW2B   = O_W2B  + 4096;             // 4096 bf16
static constexpr long long O_G2TB   = O_AW2B + 2048;             // 4096 bf16
static constexpr long long O_WFCB   = O_G2TB + 2048;             // 2560 bf16
// big buffers (bf16 activations)
static constexpr long long O_GB     = 3450004;                   // bf16 6.4M (g)
static constexpr long long O_UB     = O_GB   + 3200000;          // bf16 6.4M (u)
static constexpr long long O_HB0    = O_UB   + 3200000;          // bf16 6.4M
static constexpr long long O_HB1    = O_HB0  + 3200000;          // bf16 6.4M

__device__ __forceinline__ float bf2f(u16 u) {
    return __uint_as_float(((unsigned)u) << 16);
}
__device__ __forceinline__ u16 f2bf(float f) {
    unsigned u = __float_as_uint(f);
    return (u16)((u + 0x7FFFu + ((u >> 16) & 1u)) >> 16);
}
// fast tanh: (e^{2x}-1)/(e^{2x}+1), clamped; ~6 VALU vs libm ~25
__device__ __forceinline__ float ftanh(float x) {
    float x2 = fminf(fmaxf(2.f * x, -30.f), 30.f);
    float e = __expf(x2);
    return (e - 1.f) * __builtin_amdgcn_rcpf(e + 1.f);
}

// ---- weight prep (bf16 convert/antisym/transpose) + degi zero (fused) ----
__global__ __launch_bounds__(256) void prep_kernel(
    const float* __restrict__ w_hid, const float* __restrict__ W_a1,
    const float* __restrict__ gcn1,  const float* __restrict__ w2,
    const float* __restrict__ W_a2,  const float* __restrict__ gcn2,
    const float* __restrict__ wfc,   float* __restrict__ ws)
{
    int j = blockIdx.x * 256 + threadIdx.x;
    if (j < 32768) { ((u16*)(ws+O_WHB))[j] = f2bf(w_hid[j]); return; } j -= 32768;
    if (j < 16384) { int r=j>>7, c=j&127; ((u16*)(ws+O_G1TB))[j] = f2bf(gcn1[c*128+r]); return; } j -= 16384;
    if (j < 16384) { int r=j>>7, c=j&127;
                     ((u16*)(ws+O_AW1B))[j] = f2bf(W_a1[r*128+c] - W_a1[c*128+r] - (r==c?GAMMAC:0.f));
                     return; } j -= 16384;
    if (j < 8192)  { ((u16*)(ws+O_W2B))[j] = f2bf(w2[j]); return; } j -= 8192;
    if (j < 4096)  { int r=j>>6, c=j&63;
                     ((u16*)(ws+O_AW2B))[j] = f2bf(W_a2[r*64+c] - W_a2[c*64+r] - (r==c?GAMMAC:0.f));
                     return; } j -= 4096;
    if (j < 4096)  { int r=j>>6, c=j&63; ((u16*)(ws+O_G2TB))[j] = f2bf(gcn2[c*64+r]); return; } j -= 4096;
    if (j < 2560)  { ((u16*)(ws+O_WFCB))[j] = f2bf(wfc[j]); return; } j -= 2560;
    if (j < NNODE) { ((int*)(ws+O_DEGI))[j] = 0; return; }   // fused degi zero
}

// ---- CSR build ----
__global__ __launch_bounds__(256) void deg_count_kernel(const int* __restrict__ ei,
                                                        int* __restrict__ degi) {
    int e = blockIdx.x * 256 + threadIdx.x;
    if (e < NEDGE) atomicAdd(&degi[ei[NEDGE + e]], 1);
}
__global__ __launch_bounds__(256) void psum_kernel(const int* __restrict__ degi,
                                                   float* __restrict__ dinv,
                                                   int* __restrict__ psum) {
    int i = blockIdx.x * 256 + threadIdx.x;
    int v = (i < NNODE) ? degi[i] : 0;
    if (i < NNODE) dinv[i] = rsqrtf(1.0f + (float)v);  // +1 self loop
    int t = v;
    #pragma unroll
    for (int o = 32; o > 0; o >>= 1) t += __shfl_xor(t, o);
    __shared__ int s[4];
    int lane = threadIdx.x & 63, w = threadIdx.x >> 6;
    if (lane == 0) s[w] = t;
    __syncthreads();
    if (threadIdx.x == 0) psum[blockIdx.x] = s[0] + s[1] + s[2] + s[3];
}
__global__ __launch_bounds__(256) void scan_psum_kernel(int* __restrict__ psum, int nb) {
    int t = threadIdx.x;
    int v = (t < nb) ? psum[t] : 0;
    int lane = t & 63, w = t >> 6;
    int x = v;
    #pragma unroll
    for (int o = 1; o < 64; o <<= 1) { int u = __shfl_up(x, o); if (lane >= o) x += u; }
    __shared__ int ws4[4];
    if (lane == 63) ws4[w] = x;
    __syncthreads();
    int woff = 0;
    for (int i = 0; i < w; ++i) woff += ws4[i];
    psum[t] = woff + x - v;   // exclusive
}
__global__ __launch_bounds__(256) void scan_apply_kernel(const int* __restrict__ degi,
                                                         const int* __restrict__ psum,
                                                         int* __restrict__ rowptr,
                                                         int* __restrict__ cursor) {
    int i = blockIdx.x * 256 + threadIdx.x;
    int v = (i < NNODE) ? degi[i] : 0;
    int lane = threadIdx.x & 63, w = threadIdx.x >> 6;
    int x = v;
    #pragma unroll
    for (int o = 1; o < 64; o <<= 1) { int u = __shfl_up(x, o); if (lane >= o) x += u; }
    __shared__ int ws4[4];
    if (lane == 63) ws4[w] = x;
    __syncthreads();
    int woff = 0;
    for (int k = 0; k < w; ++k) woff += ws4[k];
    int run = psum[blockIdx.x] + woff + x - v;
    if (i < NNODE) { rowptr[i] = run; cursor[i] = run; }
    if (i == NNODE - 1) rowptr[NNODE] = run + v;
}
__global__ __launch_bounds__(256) void fill_kernel(const int* __restrict__ ei,
                                                   const float* __restrict__ dinv,
                                                   int* __restrict__ cursor,
                                                   int2* __restrict__ ecsr) {
    int e = blockIdx.x * 256 + threadIdx.x;
    if (e >= NEDGE) return;
    int s = ei[e], d = ei[NEDGE + e];
    int pos = atomicAdd(&cursor[d], 1);
    int2 v;
    v.x = s;
    v.y = __float_as_int(dinv[s] * dinv[d]);
    ecsr[pos] = v;
}

// ---- MFMA GEMM: LDS-staged B, LDS-transposed epilogue ----
// DUAL=1: two passes (Bt->outB, Bt2->outB2), raw bf16 writes, A loaded once.
// EPI: 0 none(+bias), 1 leaky(+bias), 3: fused log_softmax -> outF.
template<int KS, int NT, int AF32, int LOADACT, int EPI, int DUAL>
__global__ __launch_bounds__(256, 4) void mgemm(
    const void* __restrict__ Araw,
    const u16* __restrict__ Bt,
    const u16* __restrict__ Bt2,
    const float* __restrict__ bias,
    float* __restrict__ outF,
    u16* __restrict__ outB,
    u16* __restrict__ outB2,
    int M, int Nn, int ldc)
{
    constexpr int K    = KS * 32;
    constexpr int KCHU = (K > 128) ? 128 : K;
    constexpr int KC   = KCHU / 32;
    constexpr int NCH  = K / KCHU;
    constexpr int P    = KCHU + 8;
    constexpr int ROWS = NT * 16;
    constexpr int CW   = NT * 16 + 1;
    constexpr int BSZ  = ROWS * P * 2;
    constexpr int ASZ  = 64 * CW * 4;
    constexpr int SMEM = BSZ > ASZ ? BSZ : ASZ;
    __shared__ __align__(16) char smem[SMEM];
    u16*   bl   = (u16*)smem;
    float* accL = (float*)smem;

    const int wave = threadIdx.x >> 6;
    const int lane = threadIdx.x & 63;
    const int m = lane & 15, q = lane >> 4;
    const int rowbase = blockIdx.x * 64 + wave * 16;
    const int row = rowbase + m;
    const bool rok = row < M;
    const short8 z8 = {0,0,0,0,0,0,0,0};

    short8 af[KS];
    if (AF32) {
        const float* apf = (const float*)Araw + (long long)row * K;
        #pragma unroll
        for (int k = 0; k < KS; ++k) {
            short8 t = z8;
            if (rok) {
                const float4* p = (const float4*)(apf + (k * 4 + q) * 8);
                float4 a = p[0], b = p[1];
                t[0]=(short)f2bf(a.x); t[1]=(short)f2bf(a.y); t[2]=(short)f2bf(a.z); t[3]=(short)f2bf(a.w);
                t[4]=(short)f2bf(b.x); t[5]=(short)f2bf(b.y); t[6]=(short)f2bf(b.z); t[7]=(short)f2bf(b.w);
            }
            af[k] = t;
        }
    } else {
        const short8* ap = (const short8*)((const u16*)Araw + (long long)row * K);
        #pragma unroll
        for (int k = 0; k < KS; ++k) af[k] = rok ? ap[k * 4 + q] : z8;
    }
    if (LOADACT) {
        #pragma unroll
        for (int k = 0; k < KS; ++k)
            #pragma unroll
            for (int e = 0; e < 8; ++e) {
                float f = bf2f((u16)af[k][e]);
                f = f > 0.f ? f : 0.01f * f;
                af[k][e] = (short)f2bf(f);
            }
    }

    #pragma unroll
    for (int pass = 0; pass <= DUAL; ++pass) {
        const u16* Bcur = pass ? Bt2 : Bt;
        u16* outCur = pass ? outB2 : outB;
        if (pass) __syncthreads();     // LDS reuse across passes

        f32x4 acc[NT];
        #pragma unroll
        for (int j = 0; j < NT; ++j) acc[j] = (f32x4){0.f,0.f,0.f,0.f};

        for (int ch = 0; ch < NCH; ++ch) {
            if (ch) __syncthreads();
            constexpr int CHUNKS = ROWS * (KCHU / 8);
            for (int t = threadIdx.x; t < CHUNKS; t += 256) {
                int r = t / (KCHU / 8), c = t - r * (KCHU / 8);
                short8 v = z8;
                if (r < Nn) v = *(const short8*)&Bcur[(long long)r * K + ch * KCHU + c * 8];
                *(short8*)&bl[r * P + c * 8] = v;
            }
            __syncthreads();
            #pragma unroll
            for (int j = 0; j < NT; ++j) {
                #pragma unroll
                for (int k = 0; k < KC; ++k) {
                    short8 bf_ = *(const short8*)&bl[(j * 16 + m) * P + k * 32 + q * 8];
                    acc[j] = __builtin_amdgcn_mfma_f32_16x16x32_bf16(af[ch * KC + k], bf_, acc[j], 0, 0, 0);
                }
            }
        }

        __syncthreads();            // reuse LDS for acc transpose
        #pragma unroll
        for (int j = 0; j < NT; ++j)
            #pragma unroll
            for (int r = 0; r < 4; ++r)
                accL[(wave * 16 + q * 4 + r) * CW + j * 16 + m] = acc[j][r];
        __syncthreads();

        if (EPI == 3) {
            // fused log-softmax over Nn cols per row (all in LDS)
            float mrow = 0.f, lrow = 0.f;
            if (lane < 16) {
                const float* rp = &accL[(wave * 16 + lane) * CW];
                float mx = -1e30f;
                for (int c = 0; c < Nn; ++c) mx = fmaxf(mx, rp[c] + bias[c]);
                float s = 0.f;
                for (int c = 0; c < Nn; ++c) s += expf(rp[c] + bias[c] - mx);
                mrow = mx; lrow = logf(s);
            }
            for (int rl = 0; rl < 16; ++rl) {
                float mm = __shfl(mrow, rl);
                float ll = __shfl(lrow, rl);
                int rowD = rowbase + rl;
                if (rowD < M && lane < Nn) {
                    float v = accL[(wave * 16 + rl) * CW + lane] + bias[lane];
                    outF[(long long)rowD * ldc + lane] = v - mm - ll;
                }
            }
            return;
        }

        const int c0 = lane * 2;
        if (c0 < NT * 16) {
            float2 bv = {0.f, 0.f};
            if (EPI != 0 || !DUAL) {
                if (bias) {
                    if (c0 < Nn)     bv.x = bias[c0];
                    if (c0 + 1 < Nn) bv.y = bias[c0 + 1];
                }
            }
            #pragma unroll
            for (int rl = 0; rl < 16; ++rl) {
                int rowD = rowbase + rl;
                if (rowD >= M) continue;
                float2 v = *(const float2*)&accL[(wave * 16 + rl) * CW + c0];
                long long o = (long long)rowD * ldc + c0;
                v.x += bv.x; v.y += bv.y;
                if (EPI == 1) {
                    v.x = v.x > 0.f ? v.x : 0.01f * v.x;
                    v.y = v.y > 0.f ? v.y : 0.01f * v.y;
                }
                if (c0 + 1 < Nn) {
                    if (outCur) { ushort2 ob; ob.x = f2bf(v.x); ob.y = f2bf(v.y);
                                  *(ushort2*)&outCur[o] = ob; }
                    if (!pass && outF) { *(float2*)&outF[o] = v; }
                } else if (c0 < Nn) {
                    if (outCur) outCur[o] = f2bf(v.x);
                    if (!pass && outF) outF[o] = v.x;
                }
            }
        }
    }
}

// ---- CSR gather + fused antisym update (all-lane epilogue) ----
// After the xor-butterfly reduce every lane holds the full sums, so the
// update work is split: quarter qr handles elements [qr*EL/4,(qr+1)*EL/4).
template<int HD>
__global__ __launch_bounds__(256) void gather_upd_kernel(
    const int* __restrict__ rowptr, const int2* __restrict__ ecsr,
    const float* __restrict__ dinv,
    const u16* __restrict__ gB, const u16* __restrict__ uB,
    const u16* __restrict__ hB, const float* __restrict__ bias,
    u16* __restrict__ hnB)
{
    int node = (blockIdx.x * 256 + threadIdx.x) >> 6;
    int lane = threadIdx.x & 63;
    if (node >= NNODE) return;
    const int qr = lane >> 4, l4 = lane & 15;
    const int r0 = rowptr[node], r1 = rowptr[node + 1];
    const float wself = dinv[node] * dinv[node];
    constexpr int EL = (HD == 128) ? 8 : 4;

    float a[EL];
    #pragma unroll
    for (int i = 0; i < EL; ++i) a[i] = 0.f;
    if (qr == 0) {
        if (HD == 128) {
            ushort8 gs = *(const ushort8*)&gB[(long long)node * 128 + l4 * 8];
            #pragma unroll
            for (int i = 0; i < 8; ++i) a[i] = bf2f(gs[i]) * wself;
        } else {
            ushort4 gs = *(const ushort4*)&gB[(long long)node * 64 + l4 * 4];
            a[0] = bf2f(gs.x) * wself; a[1] = bf2f(gs.y) * wself;
            a[2] = bf2f(gs.z) * wself; a[3] = bf2f(gs.w) * wself;
        }
    }

    for (int base = r0; base < r1; base += 64) {
        int idx = base + lane;
        int cs = 0; float cw = 0.f;
        if (idx < r1) { int2 ev = ecsr[idx]; cs = ev.x; cw = __int_as_float(ev.y); }
        int cnt = min(64, r1 - base);
        for (int j = 0; j < cnt; j += 4) {
            int jj = j + qr;
            int   s = __shfl(cs, jj);
            float w = __shfl(cw, jj);
            if (HD == 128) {
                ushort8 gv = *(const ushort8*)&gB[(long long)s * 128 + l4 * 8];
                #pragma unroll
                for (int i = 0; i < 8; ++i) a[i] += bf2f(gv[i]) * w;
            } else {
                ushort4 gv = *(const ushort4*)&gB[(long long)s * 64 + l4 * 4];
                a[0] += bf2f(gv.x) * w; a[1] += bf2f(gv.y) * w;
                a[2] += bf2f(gv.z) * w; a[3] += bf2f(gv.w) * w;
            }
        }
    }

    #pragma unroll
    for (int i = 0; i < EL; ++i) {
        a[i] += __shfl_xor(a[i], 16);
        a[i] += __shfl_xor(a[i], 32);
    }
    // now ALL lanes hold the full sums for columns l4*EL + i

    if (HD == 128) {
        // quarter qr handles 2 elements -> ushort2, 256B/wave coalesced
        float v0, v1;
        if      (qr == 0) { v0 = a[0]; v1 = a[1]; }
        else if (qr == 1) { v0 = a[2]; v1 = a[3]; }
        else if (qr == 2) { v0 = a[4]; v1 = a[5]; }
        else              { v0 = a[6]; v1 = a[7]; }
        long long o = (long long)node * 128 + l4 * 8 + qr * 2;
        int bi = l4 * 8 + qr * 2;
        ushort2 uu = *(const ushort2*)&uB[o];
        ushort2 hh = *(const ushort2*)&hB[o];
        ushort2 on;
        on.x = f2bf(bf2f(hh.x) + EPSC * ftanh(v0 + bf2f(uu.x) + bias[bi]));
        on.y = f2bf(bf2f(hh.y) + EPSC * ftanh(v1 + bf2f(uu.y) + bias[bi + 1]));
        *(ushort2*)&hnB[o] = on;
    } else {
        // quarter qr handles 1 element
        float v = (qr == 0) ? a[0] : (qr == 1) ? a[1] : (qr == 2) ? a[2] : a[3];
        long long o = (long long)node * 64 + l4 * 4 + qr;
        float hn = bf2f(hB[o]) + EPSC * ftanh(v + bf2f(uB[o]) + bias[l4 * 4 + qr]);
        hnB[o] = f2bf(hn);
    }
}

extern "C" void kernel_launch(void* const* d_in, const int* in_sizes, int n_in,
                              void* d_out, int out_size, void* d_ws, size_t ws_size,
                              hipStream_t stream) {
    const float* x     = (const float*)d_in[0];
    const int*   ei    = (const int*)d_in[1];
    const float* w_hid = (const float*)d_in[2];
    const float* b_hid = (const float*)d_in[3];
    const float* W_a1  = (const float*)d_in[4];
    const float* gcn1  = (const float*)d_in[5];
    const float* b_a1  = (const float*)d_in[6];
    const float* w2    = (const float*)d_in[7];
    const float* b2    = (const float*)d_in[8];
    const float* W_a2  = (const float*)d_in[9];
    const float* gcn2  = (const float*)d_in[10];
    const float* b_a2  = (const float*)d_in[11];
    const float* wfc   = (const float*)d_in[12];
    const float* bfc   = (const float*)d_in[13];
    float* ws = (float*)d_ws;
    float* out = (float*)d_out;

    float* dinv   = ws + O_DINV;
    int*   degi   = (int*)(ws + O_DEGI);
    int*   rowptr = (int*)(ws + O_ROWPTR);
    int*   cursor = (int*)(ws + O_CURSOR);
    int*   psum   = (int*)(ws + O_PSUM);
    int2*  ecsr   = (int2*)(ws + O_ECSR);
    u16* whB  = (u16*)(ws + O_WHB);
    u16* g1tB = (u16*)(ws + O_G1TB);
    u16* aw1B = (u16*)(ws + O_AW1B);
    u16* w2B  = (u16*)(ws + O_W2B);
    u16* aw2B = (u16*)(ws + O_AW2B);
    u16* g2tB = (u16*)(ws + O_G2TB);
    u16* wfcB = (u16*)(ws + O_WFCB);
    u16* gBuf = (u16*)(ws + O_GB);
    u16* uBuf = (u16*)(ws + O_UB);
    u16* hB0  = (u16*)(ws + O_HB0);
    u16* hB1  = (u16*)(ws + O_HB1);

    const int nScanB = (NNODE + 255) / 256;  // 196

    prep_kernel<<<(84480 + NNODE + 255) / 256, 256, 0, stream>>>(
        w_hid, W_a1, gcn1, w2, W_a2, gcn2, wfc, ws);
    deg_count_kernel<<<(NEDGE + 255) / 256, 256, 0, stream>>>(ei, degi);
    psum_kernel<<<nScanB, 256, 0, stream>>>(degi, dinv, psum);
    scan_psum_kernel<<<1, 256, 0, stream>>>(psum, nScanB);
    scan_apply_kernel<<<nScanB, 256, 0, stream>>>(degi, psum, rowptr, cursor);
    fill_kernel<<<(NEDGE + 255) / 256, 256, 0, stream>>>(ei, dinv, cursor, ecsr);

    const int gB = (NNODE + 63) / 64;       // 782 row-blocks
    const int gatherBlocks = (NNODE * 64 + 255) / 256;

    // h = leaky_relu(x @ w_hid^T + b_hid) -> hB0
    mgemm<8, 8, 1, 0, 1, 0><<<gB, 256, 0, stream>>>(
        x, whB, nullptr, b_hid, nullptr, hB0, nullptr, NNODE, 128, 128);

    // conv1: 3 iterations — dual GEMM (g,u) + gather-with-update
    u16* hBc = hB0; u16* hBo = hB1;
    for (int it = 0; it < 3; ++it) {
        mgemm<4, 8, 0, 0, 0, 1><<<gB, 256, 0, stream>>>(
            hBc, g1tB, aw1B, nullptr, nullptr, gBuf, uBuf, NNODE, 128, 128);
        gather_upd_kernel<128><<<gatherBlocks, 256, 0, stream>>>(
            rowptr, ecsr, dinv, gBuf, uBuf, hBc, b_a1, hBo);
        u16* tb = hBc; hBc = hBo; hBo = tb;
    }

    // h2 = leaky_relu(leaky_relu(h) @ w2^T + b2) -> hBo
    mgemm<4, 4, 0, 1, 1, 0><<<gB, 256, 0, stream>>>(
        hBc, w2B, nullptr, b2, nullptr, hBo, nullptr, NNODE, 64, 64);
    u16* h2B = hBo;
    u16* spB = hBc;   // dead, reusable

    // conv2: 1 iteration — dual GEMM + gather-update
    mgemm<2, 4, 0, 0, 0, 1><<<gB, 256, 0, stream>>>(
        h2B, g2tB, aw2B, nullptr, nullptr, gBuf, uBuf, NNODE, 64, 64);
    gather_upd_kernel<64><<<gatherBlocks, 256, 0, stream>>>(
        rowptr, ecsr, dinv, gBuf, uBuf, h2B, b_a2, spB);

    // z = h2n @ w_fc^T + b_fc, fused log-softmax -> out (fp32)
    mgemm<2, 3, 0, 0, 3, 0><<<gB, 256, 0, stream>>>(
        spB, wfcB, nullptr, bfc, out, nullptr, nullptr, NNODE, 40, 40);
}

// Round 14
// 404.958 us; speedup vs baseline: 1.1825x; 1.0686x over previous
//
#include <hip/hip_runtime.h>
#include <hip/hip_bf16.h>
#include <math.h>

typedef unsigned short u16;
using short8  = __attribute__((ext_vector_type(8))) short;
using ushort8 = __attribute__((ext_vector_type(8))) unsigned short;
using f32x4   = __attribute__((ext_vector_type(4))) float;

static constexpr int NNODE = 50000;
static constexpr int NEDGE = 600000;
static constexpr float EPSC   = 0.1f;
static constexpr float GAMMAC = 0.1f;

// ---- workspace layout (float-index offsets) ----
static constexpr long long O_DINV   = 0;                         // float 50000
static constexpr long long O_DEGI   = 50000;                     // int 50000
static constexpr long long O_ROWPTR = 100000;                    // int 50001
static constexpr long long O_CURSOR = 150004;                    // int 50000
static constexpr long long O_PSUM   = 200004;                    // int 256
static constexpr long long O_ECSR   = 200260;                    // int2 600000 (1.2M fl)
// bf16 weights
static constexpr long long O_WHB    = 1400260;                   // 32768 bf16
static constexpr long long O_G1TB   = O_WHB  + 16384;            // 16384 bf16
static constexpr long long O_AW1B   = O_G1TB + 8192;             // 16384 bf16
static constexpr long long O_W2B    = O_AW1B + 8192;             // 8192 bf16
static constexpr long long O_AW2B   = O_W2B  + 4096;             // 4096 bf16
static constexpr long long O_G2TB   = O_AW2B + 2048;             // 4096 bf16
static constexpr long long O_WFCB   = O_G2TB + 2048;             // 2560 bf16
// big buffers (bf16 activations)
static constexpr long long O_AGGB   = 3450004;                   // bf16 6.4M (Âh)
static constexpr long long O_HB0    = O_AGGB + 3200000;          // bf16 6.4M
static constexpr long long O_HB1    = O_HB0  + 3200000;          // bf16 6.4M

__device__ __forceinline__ float bf2f(u16 u) {
    return __uint_as_float(((unsigned)u) << 16);
}
__device__ __forceinline__ u16 f2bf(float f) {
    unsigned u = __float_as_uint(f);
    return (u16)((u + 0x7FFFu + ((u >> 16) & 1u)) >> 16);
}
// fast tanh: (e^{2x}-1)/(e^{2x}+1), clamped; ~6 VALU vs libm ~25
__device__ __forceinline__ float ftanh(float x) {
    float x2 = fminf(fmaxf(2.f * x, -30.f), 30.f);
    float e = __expf(x2);
    return (e - 1.f) * __builtin_amdgcn_rcpf(e + 1.f);
}

// ---- weight prep (bf16 convert/antisym/transpose) + degi zero (fused) ----
__global__ __launch_bounds__(256) void prep_kernel(
    const float* __restrict__ w_hid, const float* __restrict__ W_a1,
    const float* __restrict__ gcn1,  const float* __restrict__ w2,
    const float* __restrict__ W_a2,  const float* __restrict__ gcn2,
    const float* __restrict__ wfc,   float* __restrict__ ws)
{
    int j = blockIdx.x * 256 + threadIdx.x;
    if (j < 32768) { ((u16*)(ws+O_WHB))[j] = f2bf(w_hid[j]); return; } j -= 32768;
    if (j < 16384) { int r=j>>7, c=j&127; ((u16*)(ws+O_G1TB))[j] = f2bf(gcn1[c*128+r]); return; } j -= 16384;
    if (j < 16384) { int r=j>>7, c=j&127;
                     ((u16*)(ws+O_AW1B))[j] = f2bf(W_a1[r*128+c] - W_a1[c*128+r] - (r==c?GAMMAC:0.f));
                     return; } j -= 16384;
    if (j < 8192)  { ((u16*)(ws+O_W2B))[j] = f2bf(w2[j]); return; } j -= 8192;
    if (j < 4096)  { int r=j>>6, c=j&63;
                     ((u16*)(ws+O_AW2B))[j] = f2bf(W_a2[r*64+c] - W_a2[c*64+r] - (r==c?GAMMAC:0.f));
                     return; } j -= 4096;
    if (j < 4096)  { int r=j>>6, c=j&63; ((u16*)(ws+O_G2TB))[j] = f2bf(gcn2[c*64+r]); return; } j -= 4096;
    if (j < 2560)  { ((u16*)(ws+O_WFCB))[j] = f2bf(wfc[j]); return; } j -= 2560;
    if (j < NNODE) { ((int*)(ws+O_DEGI))[j] = 0; return; }   // fused degi zero
}

// ---- CSR build ----
__global__ __launch_bounds__(256) void deg_count_kernel(const int* __restrict__ ei,
                                                        int* __restrict__ degi) {
    int e = blockIdx.x * 256 + threadIdx.x;
    if (e < NEDGE) atomicAdd(&degi[ei[NEDGE + e]], 1);
}
__global__ __launch_bounds__(256) void psum_kernel(const int* __restrict__ degi,
                                                   float* __restrict__ dinv,
                                                   int* __restrict__ psum) {
    int i = blockIdx.x * 256 + threadIdx.x;
    int v = (i < NNODE) ? degi[i] : 0;
    if (i < NNODE) dinv[i] = rsqrtf(1.0f + (float)v);  // +1 self loop
    int t = v;
    #pragma unroll
    for (int o = 32; o > 0; o >>= 1) t += __shfl_xor(t, o);
    __shared__ int s[4];
    int lane = threadIdx.x & 63, w = threadIdx.x >> 6;
    if (lane == 0) s[w] = t;
    __syncthreads();
    if (threadIdx.x == 0) psum[blockIdx.x] = s[0] + s[1] + s[2] + s[3];
}
__global__ __launch_bounds__(256) void scan_psum_kernel(int* __restrict__ psum, int nb) {
    int t = threadIdx.x;
    int v = (t < nb) ? psum[t] : 0;
    int lane = t & 63, w = t >> 6;
    int x = v;
    #pragma unroll
    for (int o = 1; o < 64; o <<= 1) { int u = __shfl_up(x, o); if (lane >= o) x += u; }
    __shared__ int ws4[4];
    if (lane == 63) ws4[w] = x;
    __syncthreads();
    int woff = 0;
    for (int i = 0; i < w; ++i) woff += ws4[i];
    psum[t] = woff + x - v;   // exclusive
}
__global__ __launch_bounds__(256) void scan_apply_kernel(const int* __restrict__ degi,
                                                         const int* __restrict__ psum,
                                                         int* __restrict__ rowptr,
                                                         int* __restrict__ cursor) {
    int i = blockIdx.x * 256 + threadIdx.x;
    int v = (i < NNODE) ? degi[i] : 0;
    int lane = threadIdx.x & 63, w = threadIdx.x >> 6;
    int x = v;
    #pragma unroll
    for (int o = 1; o < 64; o <<= 1) { int u = __shfl_up(x, o); if (lane >= o) x += u; }
    __shared__ int ws4[4];
    if (lane == 63) ws4[w] = x;
    __syncthreads();
    int woff = 0;
    for (int k = 0; k < w; ++k) woff += ws4[k];
    int run = psum[blockIdx.x] + woff + x - v;
    if (i < NNODE) { rowptr[i] = run; cursor[i] = run; }
    if (i == NNODE - 1) rowptr[NNODE] = run + v;
}
__global__ __launch_bounds__(256) void fill_kernel(const int* __restrict__ ei,
                                                   const float* __restrict__ dinv,
                                                   int* __restrict__ cursor,
                                                   int2* __restrict__ ecsr) {
    int e = blockIdx.x * 256 + threadIdx.x;
    if (e >= NEDGE) return;
    int s = ei[e], d = ei[NEDGE + e];
    int pos = atomicAdd(&cursor[d], 1);
    int2 v;
    v.x = s;
    v.y = __float_as_int(dinv[s] * dinv[d]);
    ecsr[pos] = v;
}

// ---- MFMA GEMM (single-B): LDS-staged B, LDS-transposed epilogue ----
// EPI: 1 leaky(+bias)->outB, 3: fused log_softmax -> outF.
template<int KS, int NT, int AF32, int LOADACT, int EPI>
__global__ __launch_bounds__(256, 4) void mgemm(
    const void* __restrict__ Araw,
    const u16* __restrict__ Bt,
    const float* __restrict__ bias,
    float* __restrict__ outF,
    u16* __restrict__ outB,
    int M, int Nn, int ldc)
{
    constexpr int K    = KS * 32;
    constexpr int KCHU = (K > 128) ? 128 : K;
    constexpr int KC   = KCHU / 32;
    constexpr int NCH  = K / KCHU;
    constexpr int P    = KCHU + 8;
    constexpr int ROWS = NT * 16;
    constexpr int CW   = NT * 16 + 1;
    constexpr int BSZ  = ROWS * P * 2;
    constexpr int ASZ  = 64 * CW * 4;
    constexpr int SMEM = BSZ > ASZ ? BSZ : ASZ;
    __shared__ __align__(16) char smem[SMEM];
    u16*   bl   = (u16*)smem;
    float* accL = (float*)smem;

    const int wave = threadIdx.x >> 6;
    const int lane = threadIdx.x & 63;
    const int m = lane & 15, q = lane >> 4;
    const int rowbase = blockIdx.x * 64 + wave * 16;
    const int row = rowbase + m;
    const bool rok = row < M;
    const short8 z8 = {0,0,0,0,0,0,0,0};

    short8 af[KS];
    if (AF32) {
        const float* apf = (const float*)Araw + (long long)row * K;
        #pragma unroll
        for (int k = 0; k < KS; ++k) {
            short8 t = z8;
            if (rok) {
                const float4* p = (const float4*)(apf + (k * 4 + q) * 8);
                float4 a = p[0], b = p[1];
                t[0]=(short)f2bf(a.x); t[1]=(short)f2bf(a.y); t[2]=(short)f2bf(a.z); t[3]=(short)f2bf(a.w);
                t[4]=(short)f2bf(b.x); t[5]=(short)f2bf(b.y); t[6]=(short)f2bf(b.z); t[7]=(short)f2bf(b.w);
            }
            af[k] = t;
        }
    } else {
        const short8* ap = (const short8*)((const u16*)Araw + (long long)row * K);
        #pragma unroll
        for (int k = 0; k < KS; ++k) af[k] = rok ? ap[k * 4 + q] : z8;
    }
    if (LOADACT) {
        #pragma unroll
        for (int k = 0; k < KS; ++k)
            #pragma unroll
            for (int e = 0; e < 8; ++e) {
                float f = bf2f((u16)af[k][e]);
                f = f > 0.f ? f : 0.01f * f;
                af[k][e] = (short)f2bf(f);
            }
    }

    f32x4 acc[NT];
    #pragma unroll
    for (int j = 0; j < NT; ++j) acc[j] = (f32x4){0.f,0.f,0.f,0.f};

    for (int ch = 0; ch < NCH; ++ch) {
        if (ch) __syncthreads();
        constexpr int CHUNKS = ROWS * (KCHU / 8);
        for (int t = threadIdx.x; t < CHUNKS; t += 256) {
            int r = t / (KCHU / 8), c = t - r * (KCHU / 8);
            short8 v = z8;
            if (r < Nn) v = *(const short8*)&Bt[(long long)r * K + ch * KCHU + c * 8];
            *(short8*)&bl[r * P + c * 8] = v;
        }
        __syncthreads();
        #pragma unroll
        for (int j = 0; j < NT; ++j) {
            #pragma unroll
            for (int k = 0; k < KC; ++k) {
                short8 bf_ = *(const short8*)&bl[(j * 16 + m) * P + k * 32 + q * 8];
                acc[j] = __builtin_amdgcn_mfma_f32_16x16x32_bf16(af[ch * KC + k], bf_, acc[j], 0, 0, 0);
            }
        }
    }

    __syncthreads();
    #pragma unroll
    for (int j = 0; j < NT; ++j)
        #pragma unroll
        for (int r = 0; r < 4; ++r)
            accL[(wave * 16 + q * 4 + r) * CW + j * 16 + m] = acc[j][r];
    __syncthreads();

    if (EPI == 3) {
        float mrow = 0.f, lrow = 0.f;
        if (lane < 16) {
            const float* rp = &accL[(wave * 16 + lane) * CW];
            float mx = -1e30f;
            for (int c = 0; c < Nn; ++c) mx = fmaxf(mx, rp[c] + bias[c]);
            float s = 0.f;
            for (int c = 0; c < Nn; ++c) s += expf(rp[c] + bias[c] - mx);
            mrow = mx; lrow = logf(s);
        }
        for (int rl = 0; rl < 16; ++rl) {
            float mm = __shfl(mrow, rl);
            float ll = __shfl(lrow, rl);
            int rowD = rowbase + rl;
            if (rowD < M && lane < Nn) {
                float v = accL[(wave * 16 + rl) * CW + lane] + bias[lane];
                outF[(long long)rowD * ldc + lane] = v - mm - ll;
            }
        }
        return;
    }

    const int c0 = lane * 2;
    if (c0 < NT * 16) {
        float2 bv = {0.f, 0.f};
        if (bias) {
            if (c0 < Nn)     bv.x = bias[c0];
            if (c0 + 1 < Nn) bv.y = bias[c0 + 1];
        }
        #pragma unroll
        for (int rl = 0; rl < 16; ++rl) {
            int rowD = rowbase + rl;
            if (rowD >= M) continue;
            float2 v = *(const float2*)&accL[(wave * 16 + rl) * CW + c0];
            long long o = (long long)rowD * ldc + c0;
            v.x += bv.x; v.y += bv.y;
            if (EPI == 1) {
                v.x = v.x > 0.f ? v.x : 0.01f * v.x;
                v.y = v.y > 0.f ? v.y : 0.01f * v.y;
            }
            if (c0 + 1 < Nn) {
                if (outB) { ushort2 ob; ob.x = f2bf(v.x); ob.y = f2bf(v.y);
                            *(ushort2*)&outB[o] = ob; }
                if (outF) { *(float2*)&outF[o] = v; }
            } else if (c0 < Nn) {
                if (outB) outB[o] = f2bf(v.x);
                if (outF) outF[o] = v.x;
            }
        }
    }
}

// ---- conv-step GEMM: acc = h@aW^T + (Âh)@G, epilogue h+eps*tanh(acc+b) ----
// Two A operands (h, Âh), two B matrices staged sequentially through one LDS,
// single accumulator / transpose / epilogue. K = KS*32 <= 128.
template<int KS, int NT>
__global__ __launch_bounds__(256, 4) void mgemm_conv(
    const u16* __restrict__ hA,      // h  [M,K] bf16
    const u16* __restrict__ gA,      // Âh [M,K] bf16
    const u16* __restrict__ BtW,     // aW  (row j = aW[j][*])
    const u16* __restrict__ BtG,     // G^T (row j = G[*][j])
    const float* __restrict__ bias,
    u16* __restrict__ outB,
    int M)
{
    constexpr int K    = KS * 32;
    constexpr int Nn   = NT * 16;    // == K for square conv weights
    constexpr int P    = K + 8;
    constexpr int CW   = Nn + 1;
    constexpr int BSZ  = Nn * P * 2;
    constexpr int ASZ  = 64 * CW * 4;
    constexpr int SMEM = BSZ > ASZ ? BSZ : ASZ;
    __shared__ __align__(16) char smem[SMEM];
    u16*   bl   = (u16*)smem;
    float* accL = (float*)smem;

    const int wave = threadIdx.x >> 6;
    const int lane = threadIdx.x & 63;
    const int m = lane & 15, q = lane >> 4;
    const int rowbase = blockIdx.x * 64 + wave * 16;
    const int row = rowbase + m;
    const bool rok = row < M;
    const short8 z8 = {0,0,0,0,0,0,0,0};

    short8 af1[KS], af2[KS];
    {
        const short8* ap1 = (const short8*)(hA + (long long)row * K);
        const short8* ap2 = (const short8*)(gA + (long long)row * K);
        #pragma unroll
        for (int k = 0; k < KS; ++k) {
            af1[k] = rok ? ap1[k * 4 + q] : z8;
            af2[k] = rok ? ap2[k * 4 + q] : z8;
        }
    }

    f32x4 acc[NT];
    #pragma unroll
    for (int j = 0; j < NT; ++j) acc[j] = (f32x4){0.f,0.f,0.f,0.f};

    #pragma unroll
    for (int pass = 0; pass < 2; ++pass) {
        const u16* Bcur = pass ? BtG : BtW;
        if (pass) __syncthreads();   // protect bl reuse
        constexpr int CHUNKS = Nn * (K / 8);
        for (int t = threadIdx.x; t < CHUNKS; t += 256) {
            int r = t / (K / 8), c = t - r * (K / 8);
            *(short8*)&bl[r * P + c * 8] = *(const short8*)&Bcur[(long long)r * K + c * 8];
        }
        __syncthreads();
        #pragma unroll
        for (int j = 0; j < NT; ++j) {
            #pragma unroll
            for (int k = 0; k < KS; ++k) {
                short8 bf_ = *(const short8*)&bl[(j * 16 + m) * P + k * 32 + q * 8];
                acc[j] = __builtin_amdgcn_mfma_f32_16x16x32_bf16(
                    pass ? af2[k] : af1[k], bf_, acc[j], 0, 0, 0);
            }
        }
    }

    __syncthreads();
    #pragma unroll
    for (int j = 0; j < NT; ++j)
        #pragma unroll
        for (int r = 0; r < 4; ++r)
            accL[(wave * 16 + q * 4 + r) * CW + j * 16 + m] = acc[j][r];
    __syncthreads();

    const int c0 = lane * 2;
    if (c0 < Nn) {
        float2 bv;
        bv.x = bias[c0]; bv.y = bias[c0 + 1];
        #pragma unroll
        for (int rl = 0; rl < 16; ++rl) {
            int rowD = rowbase + rl;
            if (rowD >= M) continue;
            float2 v = *(const float2*)&accL[(wave * 16 + rl) * CW + c0];
            long long o = (long long)rowD * Nn + c0;
            ushort2 hh = *(const ushort2*)&hA[o];
            ushort2 ob;
            ob.x = f2bf(bf2f(hh.x) + EPSC * ftanh(v.x + bv.x));
            ob.y = f2bf(bf2f(hh.y) + EPSC * ftanh(v.y + bv.y));
            *(ushort2*)&outB[o] = ob;
        }
    }
}

// ---- pure CSR gather (bf16): agg = Â h, four 16-lane quarters, 16B loads ----
template<int HD>
__global__ __launch_bounds__(256) void gather_kernel(
    const int* __restrict__ rowptr, const int2* __restrict__ ecsr,
    const float* __restrict__ dinv,
    const u16* __restrict__ gB, u16* __restrict__ aggB)
{
    int node = (blockIdx.x * 256 + threadIdx.x) >> 6;
    int lane = threadIdx.x & 63;
    if (node >= NNODE) return;
    const int qr = lane >> 4, l4 = lane & 15;
    const int r0 = rowptr[node], r1 = rowptr[node + 1];
    const float wself = dinv[node] * dinv[node];
    constexpr int EL = (HD == 128) ? 8 : 4;

    float a[EL];
    #pragma unroll
    for (int i = 0; i < EL; ++i) a[i] = 0.f;
    if (qr == 0) {
        if (HD == 128) {
            ushort8 gs = *(const ushort8*)&gB[(long long)node * 128 + l4 * 8];
            #pragma unroll
            for (int i = 0; i < 8; ++i) a[i] = bf2f(gs[i]) * wself;
        } else {
            ushort4 gs = *(const ushort4*)&gB[(long long)node * 64 + l4 * 4];
            a[0] = bf2f(gs.x) * wself; a[1] = bf2f(gs.y) * wself;
            a[2] = bf2f(gs.z) * wself; a[3] = bf2f(gs.w) * wself;
        }
    }

    for (int base = r0; base < r1; base += 64) {
        int idx = base + lane;
        int cs = 0; float cw = 0.f;
        if (idx < r1) { int2 ev = ecsr[idx]; cs = ev.x; cw = __int_as_float(ev.y); }
        int cnt = min(64, r1 - base);
        for (int j = 0; j < cnt; j += 4) {
            int jj = j + qr;
            int   s = __shfl(cs, jj);
            float w = __shfl(cw, jj);
            if (HD == 128) {
                ushort8 gv = *(const ushort8*)&gB[(long long)s * 128 + l4 * 8];
                #pragma unroll
                for (int i = 0; i < 8; ++i) a[i] += bf2f(gv[i]) * w;
            } else {
                ushort4 gv = *(const ushort4*)&gB[(long long)s * 64 + l4 * 4];
                a[0] += bf2f(gv.x) * w; a[1] += bf2f(gv.y) * w;
                a[2] += bf2f(gv.z) * w; a[3] += bf2f(gv.w) * w;
            }
        }
    }

    #pragma unroll
    for (int i = 0; i < EL; ++i) {
        a[i] += __shfl_xor(a[i], 16);
        a[i] += __shfl_xor(a[i], 32);
    }
    // all lanes hold full sums; quarter qr writes its slice (coalesced)
    if (HD == 128) {
        float v0 = (qr == 0) ? a[0] : (qr == 1) ? a[2] : (qr == 2) ? a[4] : a[6];
        float v1 = (qr == 0) ? a[1] : (qr == 1) ? a[3] : (qr == 2) ? a[5] : a[7];
        long long o = (long long)node * 128 + l4 * 8 + qr * 2;
        ushort2 ob; ob.x = f2bf(v0); ob.y = f2bf(v1);
        *(ushort2*)&aggB[o] = ob;
    } else {
        float v = (qr == 0) ? a[0] : (qr == 1) ? a[1] : (qr == 2) ? a[2] : a[3];
        aggB[(long long)node * 64 + l4 * 4 + qr] = f2bf(v);
    }
}

extern "C" void kernel_launch(void* const* d_in, const int* in_sizes, int n_in,
                              void* d_out, int out_size, void* d_ws, size_t ws_size,
                              hipStream_t stream) {
    const float* x     = (const float*)d_in[0];
    const int*   ei    = (const int*)d_in[1];
    const float* w_hid = (const float*)d_in[2];
    const float* b_hid = (const float*)d_in[3];
    const float* W_a1  = (const float*)d_in[4];
    const float* gcn1  = (const float*)d_in[5];
    const float* b_a1  = (const float*)d_in[6];
    const float* w2    = (const float*)d_in[7];
    const float* b2    = (const float*)d_in[8];
    const float* W_a2  = (const float*)d_in[9];
    const float* gcn2  = (const float*)d_in[10];
    const float* b_a2  = (const float*)d_in[11];
    const float* wfc   = (const float*)d_in[12];
    const float* bfc   = (const float*)d_in[13];
    float* ws = (float*)d_ws;
    float* out = (float*)d_out;

    float* dinv   = ws + O_DINV;
    int*   degi   = (int*)(ws + O_DEGI);
    int*   rowptr = (int*)(ws + O_ROWPTR);
    int*   cursor = (int*)(ws + O_CURSOR);
    int*   psum   = (int*)(ws + O_PSUM);
    int2*  ecsr   = (int2*)(ws + O_ECSR);
    u16* whB  = (u16*)(ws + O_WHB);
    u16* g1tB = (u16*)(ws + O_G1TB);
    u16* aw1B = (u16*)(ws + O_AW1B);
    u16* w2B  = (u16*)(ws + O_W2B);
    u16* aw2B = (u16*)(ws + O_AW2B);
    u16* g2tB = (u16*)(ws + O_G2TB);
    u16* wfcB = (u16*)(ws + O_WFCB);
    u16* aggB = (u16*)(ws + O_AGGB);
    u16* hB0  = (u16*)(ws + O_HB0);
    u16* hB1  = (u16*)(ws + O_HB1);

    const int nScanB = (NNODE + 255) / 256;  // 196

    prep_kernel<<<(84480 + NNODE + 255) / 256, 256, 0, stream>>>(
        w_hid, W_a1, gcn1, w2, W_a2, gcn2, wfc, ws);
    deg_count_kernel<<<(NEDGE + 255) / 256, 256, 0, stream>>>(ei, degi);
    psum_kernel<<<nScanB, 256, 0, stream>>>(degi, dinv, psum);
    scan_psum_kernel<<<1, 256, 0, stream>>>(psum, nScanB);
    scan_apply_kernel<<<nScanB, 256, 0, stream>>>(degi, psum, rowptr, cursor);
    fill_kernel<<<(NEDGE + 255) / 256, 256, 0, stream>>>(ei, dinv, cursor, ecsr);

    const int gB = (NNODE + 63) / 64;       // 782 row-blocks
    const int gatherBlocks = (NNODE * 64 + 255) / 256;

    // h = leaky_relu(x @ w_hid^T + b_hid) -> hB0
    mgemm<8, 8, 1, 0, 1><<<gB, 256, 0, stream>>>(
        x, whB, b_hid, nullptr, hB0, NNODE, 128, 128);

    // conv1: 3 iterations — gather(Âh) then fused conv GEMM
    u16* hBc = hB0; u16* hBo = hB1;
    for (int it = 0; it < 3; ++it) {
        gather_kernel<128><<<gatherBlocks, 256, 0, stream>>>(
            rowptr, ecsr, dinv, hBc, aggB);
        mgemm_conv<4, 8><<<gB, 256, 0, stream>>>(
            hBc, aggB, aw1B, g1tB, b_a1, hBo, NNODE);
        u16* tb = hBc; hBc = hBo; hBo = tb;
    }

    // h2 = leaky_relu(leaky_relu(h) @ w2^T + b2) -> hBo
    mgemm<4, 4, 0, 1, 1><<<gB, 256, 0, stream>>>(
        hBc, w2B, b2, nullptr, hBo, NNODE, 64, 64);
    u16* h2B = hBo;
    u16* spB = hBc;   // dead, reusable

    // conv2: 1 iteration
    gather_kernel<64><<<gatherBlocks, 256, 0, stream>>>(
        rowptr, ecsr, dinv, h2B, aggB);
    mgemm_conv<2, 4><<<gB, 256, 0, stream>>>(
        h2B, aggB, aw2B, g2tB, b_a2, spB, NNODE);

    // z = h2n @ w_fc^T + b_fc, fused log-softmax -> out (fp32)
    mgemm<2, 3, 0, 0, 3><<<gB, 256, 0, stream>>>(
        spB, wfcB, bfc, out, nullptr, NNODE, 40, 40);
}

// Round 15
// 396.555 us; speedup vs baseline: 1.2076x; 1.0212x over previous
//
#include <hip/hip_runtime.h>
#include <hip/hip_bf16.h>
#include <math.h>

typedef unsigned short u16;
typedef unsigned int   u32;
using short8  = __attribute__((ext_vector_type(8))) short;
using ushort8 = __attribute__((ext_vector_type(8))) unsigned short;
using f32x4   = __attribute__((ext_vector_type(4))) float;

static constexpr int NNODE = 50000;
static constexpr int NEDGE = 600000;
static constexpr float EPSC   = 0.1f;
static constexpr float GAMMAC = 0.1f;

// ---- workspace layout (float-index offsets) ----
static constexpr long long O_DINV   = 0;                         // float 50000
static constexpr long long O_DEGI   = 50000;                     // int 50000
static constexpr long long O_ROWPTR = 100000;                    // int 50000
static constexpr long long O_CURSOR = 150004;                    // int 50000
static constexpr long long O_GCUR   = 200052;                    // int 1
static constexpr long long O_ECSR   = 200260;                    // int2 600000 (1.2M fl)
// bf16 weights
static constexpr long long O_WHB    = 1400260;                   // 32768 bf16
static constexpr long long O_G1TB   = O_WHB  + 16384;            // 16384 bf16
static constexpr long long O_AW1B   = O_G1TB + 8192;             // 16384 bf16
static constexpr long long O_W2B    = O_AW1B + 8192;             // 8192 bf16
static constexpr long long O_AW2B   = O_W2B  + 4096;             // 4096 bf16
static constexpr long long O_G2TB   = O_AW2B + 2048;             // 4096 bf16
static constexpr long long O_WFCB   = O_G2TB + 2048;             // 2560 bf16
// big buffers
static constexpr long long O_AGGB   = 3450004;                   // bf16 6.4M (Âh)
static constexpr long long O_HB0    = O_AGGB + 3200000;          // bf16 6.4M
static constexpr long long O_HB1    = O_HB0  + 3200000;          // bf16 6.4M
static constexpr long long O_S0     = O_HB1  + 3200000;          // fp8 6.4M (1.6M fl)
static constexpr long long O_S1     = O_S0   + 1600000;          // fp8 6.4M

__device__ __forceinline__ float bf2f(u16 u) {
    return __uint_as_float(((unsigned)u) << 16);
}
__device__ __forceinline__ u16 f2bf(float f) {
    unsigned u = __float_as_uint(f);
    return (u16)((u + 0x7FFFu + ((u >> 16) & 1u)) >> 16);
}
// fast tanh: (e^{2x}-1)/(e^{2x}+1), clamped
__device__ __forceinline__ float ftanh(float x) {
    float x2 = fminf(fmaxf(2.f * x, -30.f), 30.f);
    float e = __expf(x2);
    return (e - 1.f) * __builtin_amdgcn_rcpf(e + 1.f);
}
// fp8 e4m3 pack/decode
__device__ __forceinline__ u16 pk_fp8(float a, float b) {
    int pk = __builtin_amdgcn_cvt_pk_fp8_f32(a, b, 0, false);
    return (u16)(pk & 0xffff);
}
__device__ __forceinline__ void acc_fp8x4(float* a, u32 v, float w) {
    a[0] += __builtin_amdgcn_cvt_f32_fp8(v, 0) * w;
    a[1] += __builtin_amdgcn_cvt_f32_fp8(v, 1) * w;
    a[2] += __builtin_amdgcn_cvt_f32_fp8(v, 2) * w;
    a[3] += __builtin_amdgcn_cvt_f32_fp8(v, 3) * w;
}

// ---- weight prep + degi zero + gcur zero (fused) ----
__global__ __launch_bounds__(256) void prep_kernel(
    const float* __restrict__ w_hid, const float* __restrict__ W_a1,
    const float* __restrict__ gcn1,  const float* __restrict__ w2,
    const float* __restrict__ W_a2,  const float* __restrict__ gcn2,
    const float* __restrict__ wfc,   float* __restrict__ ws)
{
    int j = blockIdx.x * 256 + threadIdx.x;
    if (j < 32768) { ((u16*)(ws+O_WHB))[j] = f2bf(w_hid[j]); return; } j -= 32768;
    if (j < 16384) { int r=j>>7, c=j&127; ((u16*)(ws+O_G1TB))[j] = f2bf(gcn1[c*128+r]); return; } j -= 16384;
    if (j < 16384) { int r=j>>7, c=j&127;
                     ((u16*)(ws+O_AW1B))[j] = f2bf(W_a1[r*128+c] - W_a1[c*128+r] - (r==c?GAMMAC:0.f));
                     return; } j -= 16384;
    if (j < 8192)  { ((u16*)(ws+O_W2B))[j] = f2bf(w2[j]); return; } j -= 8192;
    if (j < 4096)  { int r=j>>6, c=j&63;
                     ((u16*)(ws+O_AW2B))[j] = f2bf(W_a2[r*64+c] - W_a2[c*64+r] - (r==c?GAMMAC:0.f));
                     return; } j -= 4096;
    if (j < 4096)  { int r=j>>6, c=j&63; ((u16*)(ws+O_G2TB))[j] = f2bf(gcn2[c*64+r]); return; } j -= 4096;
    if (j < 2560)  { ((u16*)(ws+O_WFCB))[j] = f2bf(wfc[j]); return; } j -= 2560;
    if (j < NNODE) { ((int*)(ws+O_DEGI))[j] = 0; return; } j -= NNODE;
    if (j == 0)    { ((int*)(ws+O_GCUR))[0] = 0; }
}

// ---- CSR build ----
__global__ __launch_bounds__(256) void deg_count_kernel(const int* __restrict__ ei,
                                                        int* __restrict__ degi) {
    int e = blockIdx.x * 256 + threadIdx.x;
    if (e < NEDGE) atomicAdd(&degi[ei[NEDGE + e]], 1);
}
// atomic range allocation (order-free CSR) + dinv; replaces the 3-kernel scan
__global__ __launch_bounds__(256) void alloc_kernel(const int* __restrict__ degi,
                                                    float* __restrict__ dinv,
                                                    int* __restrict__ rowptr,
                                                    int* __restrict__ cursor,
                                                    int* __restrict__ gcur) {
    int i = blockIdx.x * 256 + threadIdx.x;
    if (i >= NNODE) return;
    int d = degi[i];
    dinv[i] = rsqrtf(1.0f + (float)d);   // +1 self loop
    int pos = atomicAdd(gcur, d);        // wave-coalesced by atomic optimizer
    rowptr[i] = pos;
    cursor[i] = pos;
}
__global__ __launch_bounds__(256) void fill_kernel(const int* __restrict__ ei,
                                                   const float* __restrict__ dinv,
                                                   int* __restrict__ cursor,
                                                   int2* __restrict__ ecsr) {
    int e = blockIdx.x * 256 + threadIdx.x;
    if (e >= NEDGE) return;
    int s = ei[e], d = ei[NEDGE + e];
    int pos = atomicAdd(&cursor[d], 1);
    int2 v;
    v.x = s;
    v.y = __float_as_int(dinv[s] * dinv[d]);
    ecsr[pos] = v;
}

// ---- MFMA GEMM (single-B): LDS-staged B, LDS-transposed epilogue ----
// EPI: 1 leaky(+bias)->outB (+fp8 shadow), 3: fused log_softmax -> outF.
template<int KS, int NT, int AF32, int LOADACT, int EPI>
__global__ __launch_bounds__(256, 4) void mgemm(
    const void* __restrict__ Araw,
    const u16* __restrict__ Bt,
    const float* __restrict__ bias,
    float* __restrict__ outF,
    u16* __restrict__ outB,
    u16* __restrict__ outB8,     // fp8 shadow (u16 = 2 fp8), may be null
    int M, int Nn, int ldc)
{
    constexpr int K    = KS * 32;
    constexpr int KCHU = (K > 128) ? 128 : K;
    constexpr int KC   = KCHU / 32;
    constexpr int NCH  = K / KCHU;
    constexpr int P    = KCHU + 8;
    constexpr int ROWS = NT * 16;
    constexpr int CW   = NT * 16 + 1;
    constexpr int BSZ  = ROWS * P * 2;
    constexpr int ASZ  = 64 * CW * 4;
    constexpr int SMEM = BSZ > ASZ ? BSZ : ASZ;
    __shared__ __align__(16) char smem[SMEM];
    u16*   bl   = (u16*)smem;
    float* accL = (float*)smem;

    const int wave = threadIdx.x >> 6;
    const int lane = threadIdx.x & 63;
    const int m = lane & 15, q = lane >> 4;
    const int rowbase = blockIdx.x * 64 + wave * 16;
    const int row = rowbase + m;
    const bool rok = row < M;
    const short8 z8 = {0,0,0,0,0,0,0,0};

    short8 af[KS];
    if (AF32) {
        const float* apf = (const float*)Araw + (long long)row * K;
        #pragma unroll
        for (int k = 0; k < KS; ++k) {
            short8 t = z8;
            if (rok) {
                const float4* p = (const float4*)(apf + (k * 4 + q) * 8);
                float4 a = p[0], b = p[1];
                t[0]=(short)f2bf(a.x); t[1]=(short)f2bf(a.y); t[2]=(short)f2bf(a.z); t[3]=(short)f2bf(a.w);
                t[4]=(short)f2bf(b.x); t[5]=(short)f2bf(b.y); t[6]=(short)f2bf(b.z); t[7]=(short)f2bf(b.w);
            }
            af[k] = t;
        }
    } else {
        const short8* ap = (const short8*)((const u16*)Araw + (long long)row * K);
        #pragma unroll
        for (int k = 0; k < KS; ++k) af[k] = rok ? ap[k * 4 + q] : z8;
    }
    if (LOADACT) {
        #pragma unroll
        for (int k = 0; k < KS; ++k)
            #pragma unroll
            for (int e = 0; e < 8; ++e) {
                float f = bf2f((u16)af[k][e]);
                f = f > 0.f ? f : 0.01f * f;
                af[k][e] = (short)f2bf(f);
            }
    }

    f32x4 acc[NT];
    #pragma unroll
    for (int j = 0; j < NT; ++j) acc[j] = (f32x4){0.f,0.f,0.f,0.f};

    for (int ch = 0; ch < NCH; ++ch) {
        if (ch) __syncthreads();
        constexpr int CHUNKS = ROWS * (KCHU / 8);
        for (int t = threadIdx.x; t < CHUNKS; t += 256) {
            int r = t / (KCHU / 8), c = t - r * (KCHU / 8);
            short8 v = z8;
            if (r < Nn) v = *(const short8*)&Bt[(long long)r * K + ch * KCHU + c * 8];
            *(short8*)&bl[r * P + c * 8] = v;
        }
        __syncthreads();
        #pragma unroll
        for (int j = 0; j < NT; ++j) {
            #pragma unroll
            for (int k = 0; k < KC; ++k) {
                short8 bf_ = *(const short8*)&bl[(j * 16 + m) * P + k * 32 + q * 8];
                acc[j] = __builtin_amdgcn_mfma_f32_16x16x32_bf16(af[ch * KC + k], bf_, acc[j], 0, 0, 0);
            }
        }
    }

    __syncthreads();
    #pragma unroll
    for (int j = 0; j < NT; ++j)
        #pragma unroll
        for (int r = 0; r < 4; ++r)
            accL[(wave * 16 + q * 4 + r) * CW + j * 16 + m] = acc[j][r];
    __syncthreads();

    if (EPI == 3) {
        float mrow = 0.f, lrow = 0.f;
        if (lane < 16) {
            const float* rp = &accL[(wave * 16 + lane) * CW];
            float mx = -1e30f;
            for (int c = 0; c < Nn; ++c) mx = fmaxf(mx, rp[c] + bias[c]);
            float s = 0.f;
            for (int c = 0; c < Nn; ++c) s += expf(rp[c] + bias[c] - mx);
            mrow = mx; lrow = logf(s);
        }
        for (int rl = 0; rl < 16; ++rl) {
            float mm = __shfl(mrow, rl);
            float ll = __shfl(lrow, rl);
            int rowD = rowbase + rl;
            if (rowD < M && lane < Nn) {
                float v = accL[(wave * 16 + rl) * CW + lane] + bias[lane];
                outF[(long long)rowD * ldc + lane] = v - mm - ll;
            }
        }
        return;
    }

    const int c0 = lane * 2;
    if (c0 < NT * 16) {
        float2 bv = {0.f, 0.f};
        if (bias) {
            if (c0 < Nn)     bv.x = bias[c0];
            if (c0 + 1 < Nn) bv.y = bias[c0 + 1];
        }
        #pragma unroll
        for (int rl = 0; rl < 16; ++rl) {
            int rowD = rowbase + rl;
            if (rowD >= M) continue;
            float2 v = *(const float2*)&accL[(wave * 16 + rl) * CW + c0];
            long long o = (long long)rowD * ldc + c0;
            v.x += bv.x; v.y += bv.y;
            if (EPI == 1) {
                v.x = v.x > 0.f ? v.x : 0.01f * v.x;
                v.y = v.y > 0.f ? v.y : 0.01f * v.y;
            }
            if (c0 + 1 < Nn) {
                if (outB) { ushort2 ob; ob.x = f2bf(v.x); ob.y = f2bf(v.y);
                            *(ushort2*)&outB[o] = ob; }
                if (outB8) outB8[o >> 1] = pk_fp8(v.x, v.y);
                if (outF) { *(float2*)&outF[o] = v; }
            } else if (c0 < Nn) {
                if (outB) outB[o] = f2bf(v.x);
                if (outF) outF[o] = v.x;
            }
        }
    }
}

// ---- conv-step GEMM: acc = h@aW^T + (Âh)@G, epi h+eps*tanh(acc+b) ----
template<int KS, int NT>
__global__ __launch_bounds__(256, 4) void mgemm_conv(
    const u16* __restrict__ hA,      // h  [M,K] bf16
    const u16* __restrict__ gA,      // Âh [M,K] bf16
    const u16* __restrict__ BtW,
    const u16* __restrict__ BtG,
    const float* __restrict__ bias,
    u16* __restrict__ outB,
    u16* __restrict__ outB8,         // fp8 shadow of h_new, may be null
    int M)
{
    constexpr int K    = KS * 32;
    constexpr int Nn   = NT * 16;
    constexpr int P    = K + 8;
    constexpr int CW   = Nn + 1;
    constexpr int BSZ  = Nn * P * 2;
    constexpr int ASZ  = 64 * CW * 4;
    constexpr int SMEM = BSZ > ASZ ? BSZ : ASZ;
    __shared__ __align__(16) char smem[SMEM];
    u16*   bl   = (u16*)smem;
    float* accL = (float*)smem;

    const int wave = threadIdx.x >> 6;
    const int lane = threadIdx.x & 63;
    const int m = lane & 15, q = lane >> 4;
    const int rowbase = blockIdx.x * 64 + wave * 16;
    const int row = rowbase + m;
    const bool rok = row < M;
    const short8 z8 = {0,0,0,0,0,0,0,0};

    short8 af1[KS], af2[KS];
    {
        const short8* ap1 = (const short8*)(hA + (long long)row * K);
        const short8* ap2 = (const short8*)(gA + (long long)row * K);
        #pragma unroll
        for (int k = 0; k < KS; ++k) {
            af1[k] = rok ? ap1[k * 4 + q] : z8;
            af2[k] = rok ? ap2[k * 4 + q] : z8;
        }
    }

    f32x4 acc[NT];
    #pragma unroll
    for (int j = 0; j < NT; ++j) acc[j] = (f32x4){0.f,0.f,0.f,0.f};

    #pragma unroll
    for (int pass = 0; pass < 2; ++pass) {
        const u16* Bcur = pass ? BtG : BtW;
        if (pass) __syncthreads();
        constexpr int CHUNKS = Nn * (K / 8);
        for (int t = threadIdx.x; t < CHUNKS; t += 256) {
            int r = t / (K / 8), c = t - r * (K / 8);
            *(short8*)&bl[r * P + c * 8] = *(const short8*)&Bcur[(long long)r * K + c * 8];
        }
        __syncthreads();
        #pragma unroll
        for (int j = 0; j < NT; ++j) {
            #pragma unroll
            for (int k = 0; k < KS; ++k) {
                short8 bf_ = *(const short8*)&bl[(j * 16 + m) * P + k * 32 + q * 8];
                acc[j] = __builtin_amdgcn_mfma_f32_16x16x32_bf16(
                    pass ? af2[k] : af1[k], bf_, acc[j], 0, 0, 0);
            }
        }
    }

    __syncthreads();
    #pragma unroll
    for (int j = 0; j < NT; ++j)
        #pragma unroll
        for (int r = 0; r < 4; ++r)
            accL[(wave * 16 + q * 4 + r) * CW + j * 16 + m] = acc[j][r];
    __syncthreads();

    const int c0 = lane * 2;
    if (c0 < Nn) {
        float2 bv;
        bv.x = bias[c0]; bv.y = bias[c0 + 1];
        #pragma unroll
        for (int rl = 0; rl < 16; ++rl) {
            int rowD = rowbase + rl;
            if (rowD >= M) continue;
            float2 v = *(const float2*)&accL[(wave * 16 + rl) * CW + c0];
            long long o = (long long)rowD * Nn + c0;
            ushort2 hh = *(const ushort2*)&hA[o];
            float n0 = bf2f(hh.x) + EPSC * ftanh(v.x + bv.x);
            float n1 = bf2f(hh.y) + EPSC * ftanh(v.y + bv.y);
            ushort2 ob; ob.x = f2bf(n0); ob.y = f2bf(n1);
            *(ushort2*)&outB[o] = ob;
            if (outB8) outB8[o >> 1] = pk_fp8(n0, n1);
        }
    }
}

// ---- pure CSR gather (fp8 in, bf16 out): agg = Â h ----
template<int HD>
__global__ __launch_bounds__(256) void gather_kernel(
    const int* __restrict__ rowptr, const int* __restrict__ degi,
    const int2* __restrict__ ecsr, const float* __restrict__ dinv,
    const u32* __restrict__ g8, u16* __restrict__ aggB)
{
    int node = (blockIdx.x * 256 + threadIdx.x) >> 6;
    int lane = threadIdx.x & 63;
    if (node >= NNODE) return;
    const int qr = lane >> 4, l4 = lane & 15;
    const int r0 = rowptr[node];
    const int r1 = r0 + degi[node];
    const float wself = dinv[node] * dinv[node];
    constexpr int EL = (HD == 128) ? 8 : 4;

    float a[EL];
    #pragma unroll
    for (int i = 0; i < EL; ++i) a[i] = 0.f;
    if (qr == 0) {
        if (HD == 128) {
            uint2 gv = ((const uint2*)g8)[(long long)node * 16 + l4];
            acc_fp8x4(a, gv.x, wself);
            acc_fp8x4(a + 4, gv.y, wself);
        } else {
            u32 gv = g8[(long long)node * 16 + l4];
            acc_fp8x4(a, gv, wself);
        }
    }

    for (int base = r0; base < r1; base += 64) {
        int idx = base + lane;
        int cs = 0; float cw = 0.f;
        if (idx < r1) { int2 ev = ecsr[idx]; cs = ev.x; cw = __int_as_float(ev.y); }
        int cnt = min(64, r1 - base);
        for (int j = 0; j < cnt; j += 4) {
            int jj = j + qr;
            int   s = __shfl(cs, jj);
            float w = __shfl(cw, jj);
            if (HD == 128) {
                uint2 gv = ((const uint2*)g8)[(long long)s * 16 + l4];
                acc_fp8x4(a, gv.x, w);
                acc_fp8x4(a + 4, gv.y, w);
            } else {
                u32 gv = g8[(long long)s * 16 + l4];
                acc_fp8x4(a, gv, w);
            }
        }
    }

    #pragma unroll
    for (int i = 0; i < EL; ++i) {
        a[i] += __shfl_xor(a[i], 16);
        a[i] += __shfl_xor(a[i], 32);
    }
    if (HD == 128) {
        float v0 = (qr == 0) ? a[0] : (qr == 1) ? a[2] : (qr == 2) ? a[4] : a[6];
        float v1 = (qr == 0) ? a[1] : (qr == 1) ? a[3] : (qr == 2) ? a[5] : a[7];
        long long o = (long long)node * 128 + l4 * 8 + qr * 2;
        ushort2 ob; ob.x = f2bf(v0); ob.y = f2bf(v1);
        *(ushort2*)&aggB[o] = ob;
    } else {
        float v = (qr == 0) ? a[0] : (qr == 1) ? a[1] : (qr == 2) ? a[2] : a[3];
        aggB[(long long)node * 64 + l4 * 4 + qr] = f2bf(v);
    }
}

extern "C" void kernel_launch(void* const* d_in, const int* in_sizes, int n_in,
                              void* d_out, int out_size, void* d_ws, size_t ws_size,
                              hipStream_t stream) {
    const float* x     = (const float*)d_in[0];
    const int*   ei    = (const int*)d_in[1];
    const float* w_hid = (const float*)d_in[2];
    const float* b_hid = (const float*)d_in[3];
    const float* W_a1  = (const float*)d_in[4];
    const float* gcn1  = (const float*)d_in[5];
    const float* b_a1  = (const float*)d_in[6];
    const float* w2    = (const float*)d_in[7];
    const float* b2    = (const float*)d_in[8];
    const float* W_a2  = (const float*)d_in[9];
    const float* gcn2  = (const float*)d_in[10];
    const float* b_a2  = (const float*)d_in[11];
    const float* wfc   = (const float*)d_in[12];
    const float* bfc   = (const float*)d_in[13];
    float* ws = (float*)d_ws;
    float* out = (float*)d_out;

    float* dinv   = ws + O_DINV;
    int*   degi   = (int*)(ws + O_DEGI);
    int*   rowptr = (int*)(ws + O_ROWPTR);
    int*   cursor = (int*)(ws + O_CURSOR);
    int*   gcur   = (int*)(ws + O_GCUR);
    int2*  ecsr   = (int2*)(ws + O_ECSR);
    u16* whB  = (u16*)(ws + O_WHB);
    u16* g1tB = (u16*)(ws + O_G1TB);
    u16* aw1B = (u16*)(ws + O_AW1B);
    u16* w2B  = (u16*)(ws + O_W2B);
    u16* aw2B = (u16*)(ws + O_AW2B);
    u16* g2tB = (u16*)(ws + O_G2TB);
    u16* wfcB = (u16*)(ws + O_WFCB);
    u16* aggB = (u16*)(ws + O_AGGB);
    u16* hB0  = (u16*)(ws + O_HB0);
    u16* hB1  = (u16*)(ws + O_HB1);
    u16* s0   = (u16*)(ws + O_S0);    // fp8 shadow of hB0
    u16* s1   = (u16*)(ws + O_S1);    // fp8 shadow of hB1

    const int nNodeB = (NNODE + 255) / 256;  // 196

    prep_kernel<<<(84480 + NNODE + 256 + 255) / 256, 256, 0, stream>>>(
        w_hid, W_a1, gcn1, w2, W_a2, gcn2, wfc, ws);
    deg_count_kernel<<<(NEDGE + 255) / 256, 256, 0, stream>>>(ei, degi);
    alloc_kernel<<<nNodeB, 256, 0, stream>>>(degi, dinv, rowptr, cursor, gcur);
    fill_kernel<<<(NEDGE + 255) / 256, 256, 0, stream>>>(ei, dinv, cursor, ecsr);

    const int gB = (NNODE + 63) / 64;       // 782 row-blocks
    const int gatherBlocks = (NNODE * 64 + 255) / 256;

    // h = leaky_relu(x @ w_hid^T + b_hid) -> hB0 (+fp8 shadow s0)
    mgemm<8, 8, 1, 0, 1><<<gB, 256, 0, stream>>>(
        x, whB, b_hid, nullptr, hB0, s0, NNODE, 128, 128);

    // conv1: 3 iterations — gather(Âh from fp8) then fused conv GEMM
    u16* hBc = hB0; u16* hBo = hB1;
    u16* sC  = s0;  u16* sO  = s1;
    for (int it = 0; it < 3; ++it) {
        gather_kernel<128><<<gatherBlocks, 256, 0, stream>>>(
            rowptr, degi, ecsr, dinv, (const u32*)sC, aggB);
        mgemm_conv<4, 8><<<gB, 256, 0, stream>>>(
            hBc, aggB, aw1B, g1tB, b_a1, hBo, sO, NNODE);
        u16* tb = hBc; hBc = hBo; hBo = tb;
        u16* ts = sC;  sC = sO;  sO = ts;
    }

    // h2 = leaky_relu(leaky_relu(h) @ w2^T + b2) -> hBo (+fp8 shadow sO)
    mgemm<4, 4, 0, 1, 1><<<gB, 256, 0, stream>>>(
        hBc, w2B, b2, nullptr, hBo, sO, NNODE, 64, 64);
    u16* h2B = hBo; u16* s2 = sO;
    u16* spB = hBc;   // dead, reusable

    // conv2: 1 iteration
    gather_kernel<64><<<gatherBlocks, 256, 0, stream>>>(
        rowptr, degi, ecsr, dinv, (const u32*)s2, aggB);
    mgemm_conv<2, 4><<<gB, 256, 0, stream>>>(
        h2B, aggB, aw2B, g2tB, b_a2, spB, nullptr, NNODE);

    // z = h2n @ w_fc^T + b_fc, fused log-softmax -> out (fp32)
    mgemm<2, 3, 0, 0, 3><<<gB, 256, 0, stream>>>(
        spB, wfcB, bfc, out, nullptr, nullptr, NNODE, 40, 40);
}